// Round 1
// baseline (159.083 us; speedup 1.0000x reference)
//
#include <hip/hip_runtime.h>

// BitConv2d: x (16,32,224,224) f32, w (32,32,3,3) f32, out (16,32,224,224) f32.
// out = conv(x_q, w_q) * (x_scale/127 * w_scale); x_q in [-128,127], w_q in {-1,0,1}.
// Both exact in bf16 -> bf16 MFMA computes the integer conv exactly (|sum| < 2^24).

typedef __attribute__((ext_vector_type(8))) short short8;
typedef __attribute__((ext_vector_type(4))) float f32x4;

#define HW    224
#define C_IN  32
#define K_OUT 32
#define N_IMG 16
// conv tile: 8 rows x 32 cols per block, 4 waves (each wave: 2 rows x 32 px x 32 k)
#define TH 8
#define TW 32
// staged LDS tile: [cblk=4][(TH+2)*(TW+2)=340][8ch] bf16, 21760 B
#define STAGE_N (C_IN * (TH + 2) * (TW + 2))   // 10880 elements

__global__ __launch_bounds__(256) void absmax_kernel(const float* __restrict__ x,
                                                     unsigned* __restrict__ r, int n4)
{
    const float4* x4 = (const float4*)x;
    float m = 0.f;
    int stride = gridDim.x * blockDim.x;
    for (int i = blockIdx.x * blockDim.x + threadIdx.x; i < n4; i += stride) {
        float4 v = x4[i];
        m = fmaxf(m, fmaxf(fmaxf(fabsf(v.x), fabsf(v.y)),
                           fmaxf(fabsf(v.z), fabsf(v.w))));
    }
    #pragma unroll
    for (int off = 32; off > 0; off >>= 1)
        m = fmaxf(m, __shfl_xor(m, off));
    __shared__ float wm[4];
    int lane = threadIdx.x & 63, wv = threadIdx.x >> 6;
    if (lane == 0) wm[wv] = m;
    __syncthreads();
    if (threadIdx.x == 0) {
        m = fmaxf(fmaxf(wm[0], wm[1]), fmaxf(wm[2], wm[3]));
        atomicMax(r, __float_as_uint(m));  // nonneg floats: uint order == float order
    }
}

// ws layout: u32[0] = absmax bits; f32[1] = out_scale; f32[2] = 127/x_scale;
// byte offset 64: 9216 bf16 ternary weights in MFMA A-fragment order:
//   wbuf[((tap*2+kb)*64 + lane)*8 + j] = w_q[kb*16+(lane&15)][(lane>>4)*8+j][tap/3][tap%3]
__global__ __launch_bounds__(256) void prep_kernel(const float* __restrict__ w,
                                                   float* __restrict__ ws_f,
                                                   short* __restrict__ wbuf)
{
    float s = 0.f;
    for (int i = threadIdx.x; i < 9216; i += 256) s += fabsf(w[i]);
    #pragma unroll
    for (int off = 32; off > 0; off >>= 1) s += __shfl_xor(s, off);
    __shared__ float sm[4];
    __shared__ float s_scale;
    int lane = threadIdx.x & 63, wv = threadIdx.x >> 6;
    if (lane == 0) sm[wv] = s;
    __syncthreads();
    if (threadIdx.x == 0) {
        float tot = sm[0] + sm[1] + sm[2] + sm[3];
        float wscale = tot / 9216.f + 1e-5f;
        float xscale = __uint_as_float(((unsigned*)ws_f)[0]) + 1e-5f;
        ws_f[1] = (xscale / 127.f) * wscale;  // epilogue scale
        ws_f[2] = 127.f / xscale;             // x quant scale
        s_scale = wscale;
    }
    __syncthreads();
    float wscale = s_scale;
    for (int o = threadIdx.x; o < 9216; o += 256) {
        int frag = o >> 9;        // 0..17 = tap*2 + kb
        int rem  = o & 511;
        int l    = rem >> 3;      // lane
        int j    = rem & 7;
        int tap  = frag >> 1;
        int kb   = frag & 1;
        int kout = kb * 16 + (l & 15);
        int c    = ((l >> 4) << 3) + j;
        int r    = tap / 3, ss = tap % 3;
        float wv2 = w[((kout * 32 + c) * 3 + r) * 3 + ss];
        float q = rintf(wv2 / wscale);            // round half-even, matches jnp.round
        q = fminf(1.f, fmaxf(-1.f, q));
        wbuf[o] = (short)(__float_as_uint(q) >> 16);  // exact bf16 of {-1,0,1}
    }
}

__global__ __launch_bounds__(256) void conv_kernel(const float* __restrict__ x,
                                                   const short* __restrict__ wbuf,
                                                   const float* __restrict__ scal,
                                                   float* __restrict__ out)
{
    __shared__ __align__(16) unsigned short xs[4 * 340 * 8];

    int bid = blockIdx.x;
    int tw = bid % 7;
    int rest = bid / 7;
    int th = rest % 28;
    int n  = rest / 28;
    int h0 = th * TH, w0 = tw * TW;

    int lane = threadIdx.x & 63, wv = threadIdx.x >> 6;

    // 18 weight fragments -> 72 VGPRs, coalesced dwordx4 loads (L2-resident)
    short8 wf[18];
    #pragma unroll
    for (int f = 0; f < 18; ++f)
        wf[f] = *(const short8*)(wbuf + f * 512 + lane * 8);

    float inv = scal[2];
    float osc = scal[1];

    // stage halo tile, quantize f32 -> int -> bf16 on the fly, channel-last layout
    const float* xn = x + n * (C_IN * HW * HW);
    for (int i = threadIdx.x; i < STAGE_N; i += 256) {
        int c   = i / 340;
        int rem = i - c * 340;
        int hp  = rem / 34;
        int wp  = rem - hp * 34;
        int gh = h0 - 1 + hp;
        int gw = w0 - 1 + wp;
        float v = 0.f;
        if ((unsigned)gh < 224u && (unsigned)gw < 224u)
            v = xn[(c * HW + gh) * HW + gw];
        float q = rintf(fminf(127.f, fmaxf(-128.f, v * inv)));
        xs[((c >> 3) * 340 + hp * 34 + wp) * 8 + (c & 7)] =
            (unsigned short)(__float_as_uint(q) >> 16);
    }
    __syncthreads();

    f32x4 acc[2][2][2] = {};  // [row][pixblock][kblock], all static-indexed
    int ln = lane & 15, cb = lane >> 4;

    #pragma unroll
    for (int ri = 0; ri < 2; ++ri) {
        #pragma unroll
        for (int pb = 0; pb < 2; ++pb) {
            #pragma unroll
            for (int r = 0; r < 3; ++r) {
                #pragma unroll
                for (int s = 0; s < 3; ++s) {
                    int hp = wv * 2 + ri + r;
                    int wp = pb * 16 + ln + s;
                    // B frag: lane holds x_q[ch = (lane>>4)*8 + j][pixel = lane&15]
                    const short8 b = *(const short8*)&xs[(cb * 340 + hp * 34 + wp) * 8];
                    int tap = r * 3 + s;
                    acc[ri][pb][0] = __builtin_amdgcn_mfma_f32_16x16x32_bf16(
                        wf[tap * 2 + 0], b, acc[ri][pb][0], 0, 0, 0);
                    acc[ri][pb][1] = __builtin_amdgcn_mfma_f32_16x16x32_bf16(
                        wf[tap * 2 + 1], b, acc[ri][pb][1], 0, 0, 0);
                }
            }
        }
    }

    // epilogue: C/D layout col=lane&15 (pixel), row=(lane>>4)*4+reg (k within 16)
    float* on = out + n * (K_OUT * HW * HW);
    int m0 = (lane >> 4) * 4;
    #pragma unroll
    for (int ri = 0; ri < 2; ++ri) {
        int h = h0 + wv * 2 + ri;
        #pragma unroll
        for (int pb = 0; pb < 2; ++pb) {
            int w = w0 + pb * 16 + ln;
            #pragma unroll
            for (int kb = 0; kb < 2; ++kb) {
                #pragma unroll
                for (int reg = 0; reg < 4; ++reg) {
                    int k = kb * 16 + m0 + reg;
                    on[(k * HW + h) * HW + w] = acc[ri][pb][kb][reg] * osc;
                }
            }
        }
    }
}

extern "C" void kernel_launch(void* const* d_in, const int* in_sizes, int n_in,
                              void* d_out, int out_size, void* d_ws, size_t ws_size,
                              hipStream_t stream)
{
    const float* x = (const float*)d_in[0];
    const float* w = (const float*)d_in[1];
    float* outp = (float*)d_out;
    float* ws_f = (float*)d_ws;
    short* wbuf = (short*)((char*)d_ws + 64);

    // reset absmax accumulator (ws poisoned once, and we leave our own state behind)
    hipMemsetAsync(d_ws, 0, 64, stream);

    int n4 = (N_IMG * C_IN * HW * HW) / 4;
    absmax_kernel<<<2048, 256, 0, stream>>>(x, (unsigned*)d_ws, n4);
    prep_kernel<<<1, 256, 0, stream>>>(w, ws_f, wbuf);
    conv_kernel<<<N_IMG * (HW / TH) * (HW / TW), 256, 0, stream>>>(x, wbuf, ws_f, outp);
}

// Round 2
// 95.425 us; speedup vs baseline: 1.6671x; 1.6671x over previous
//
#include <hip/hip_runtime.h>

// BitConv2d: x (16,32,224,224) f32, w (32,32,3,3) f32, out (16,32,224,224) f32.
// out = conv(x_q, w_q) * (x_scale/127 * w_scale); x_q in [-128,127], w_q in {-1,0,1}.
// Both exact in bf16 -> bf16 MFMA computes the integer conv exactly (|sum| < 2^24).

typedef __attribute__((ext_vector_type(8))) short short8;
typedef __attribute__((ext_vector_type(4))) float f32x4;

#define HW    224
#define NCH   32
#define PLANE (HW * HW)   // 50176
#define TH 8
#define TW 32
// LDS tile: 340 pixels (10 rows x 34 cols) x 32 ch bf16, granule-XOR swizzled.

// halfword index: pixel-major, channel-last, 16B granule (8ch) XOR-swizzled so
// frag reads (pix stride 1 across lanes) and staging writes (pix stride 4) both
// spread evenly across bank quads.
__device__ __forceinline__ int lds_h(int pix, int c) {
    int sw = (pix & 3) ^ ((pix >> 2) & 3);
    return pix * 32 + (c & 7) + ((((c >> 3) ^ sw) & 3) << 3);
}

__global__ __launch_bounds__(256) void absmax_kernel(const float* __restrict__ x,
                                                     unsigned* __restrict__ slots, int n4)
{
    const float4* x4 = (const float4*)x;
    float m = 0.f;
    int stride = gridDim.x * blockDim.x;
    for (int i = blockIdx.x * blockDim.x + threadIdx.x; i < n4; i += stride) {
        float4 v = x4[i];
        m = fmaxf(m, fmaxf(fmaxf(fabsf(v.x), fabsf(v.y)),
                           fmaxf(fabsf(v.z), fabsf(v.w))));
    }
    #pragma unroll
    for (int off = 32; off > 0; off >>= 1)
        m = fmaxf(m, __shfl_xor(m, off));
    __shared__ float wm[4];
    int lane = threadIdx.x & 63, wv = threadIdx.x >> 6;
    if (lane == 0) wm[wv] = m;
    __syncthreads();
    if (threadIdx.x == 0) {
        m = fmaxf(fmaxf(wm[0], wm[1]), fmaxf(wm[2], wm[3]));
        // 64 slots in distinct 64-B lines -> ~32 atomics per line, no hot spot
        atomicMax(&slots[(blockIdx.x & 63) * 16], __float_as_uint(m));
    }
}

// ws: [0,4096) = 64 max-slots (stride 64 B); 4096: scal[0]=out_scale, scal[1]=127/xscale;
// 4608: wbuf, 18 frags x 512 bf16. Frag (tap*2+kb): lane l elem j =
//   w_q[kout = kb*16+(l&15)][c = (l>>4)*8+j][tap/3][tap%3]  (B-operand layout)
__global__ __launch_bounds__(256) void prep_kernel(const float* __restrict__ w,
                                                   const unsigned* __restrict__ slots,
                                                   float* __restrict__ scal,
                                                   unsigned short* __restrict__ wbuf)
{
    float s = 0.f;
    for (int i = threadIdx.x; i < 9216; i += 256) s += fabsf(w[i]);
    #pragma unroll
    for (int off = 32; off > 0; off >>= 1) s += __shfl_xor(s, off);
    __shared__ float sm[4];
    __shared__ float s_ws;
    int lane = threadIdx.x & 63, wv = threadIdx.x >> 6;
    if (lane == 0) sm[wv] = s;
    __syncthreads();
    float m = 0.f;
    if (threadIdx.x < 64) {
        m = __uint_as_float(slots[threadIdx.x * 16]);
        #pragma unroll
        for (int off = 32; off > 0; off >>= 1) m = fmaxf(m, __shfl_xor(m, off));
    }
    if (threadIdx.x == 0) {
        float wscale = (sm[0] + sm[1] + sm[2] + sm[3]) / 9216.f + 1e-5f;
        float xscale = m + 1e-5f;
        scal[0] = (xscale / 127.f) * wscale;  // epilogue scale
        scal[1] = 127.f / xscale;             // x quant scale
        s_ws = wscale;
    }
    __syncthreads();
    float wscale = s_ws;
    for (int o = threadIdx.x; o < 9216; o += 256) {
        int frag = o >> 9, rem = o & 511;
        int l = rem >> 3, j = rem & 7;
        int tap = frag >> 1, kb = frag & 1;
        int kout = kb * 16 + (l & 15);
        int c = ((l >> 4) << 3) + j;
        int r = tap / 3, ss = tap % 3;
        float wv2 = w[((kout * 32 + c) * 3 + r) * 3 + ss];
        float q = fminf(1.f, fmaxf(-1.f, rintf(wv2 / wscale)));
        wbuf[o] = (unsigned short)(__float_as_uint(q) >> 16);  // exact bf16 of {-1,0,1}
    }
}

__global__ __launch_bounds__(256, 4) void conv_kernel(const float* __restrict__ x,
                                                      const unsigned short* __restrict__ wbuf,
                                                      const float* __restrict__ scal,
                                                      float* __restrict__ out)
{
    __shared__ __align__(16) unsigned short xs[10880];

    // bijective XCD swizzle: 3136 blocks = 8 XCDs x 392 contiguous
    int bid = (blockIdx.x & 7) * 392 + (blockIdx.x >> 3);
    int tw = bid % 7;
    int rest = bid / 7;
    int th = rest % 28;
    int n  = rest / 28;
    int h0 = th * TH, w0 = tw * TW;

    int tid = threadIdx.x;
    int lane = tid & 63, wv = tid >> 6;

    float inv = scal[1];
    const float* xn = x + n * (NCH * PLANE);

    // ---- stage interior cols [w0, w0+32): thread = (c = tid>>3, slot = tid&7),
    // loop over 10 halo rows; block-uniform bounds check; induction addressing.
    {
        int c = tid >> 3;
        int slot = tid & 7;
        const float* tb = xn + c * PLANE + w0 + slot * 4;
        int pixb = 1 + slot * 4;
        #pragma unroll 2
        for (int hp = 0; hp < 10; ++hp) {
            int gh = h0 - 1 + hp;
            float4 v = {0.f, 0.f, 0.f, 0.f};
            if ((unsigned)gh < (unsigned)HW) v = *(const float4*)(tb + gh * HW);
            int p0 = hp * 34 + pixb;
            float q0 = rintf(fminf(127.f, fmaxf(-128.f, v.x * inv)));
            float q1 = rintf(fminf(127.f, fmaxf(-128.f, v.y * inv)));
            float q2 = rintf(fminf(127.f, fmaxf(-128.f, v.z * inv)));
            float q3 = rintf(fminf(127.f, fmaxf(-128.f, v.w * inv)));
            xs[lds_h(p0 + 0, c)] = (unsigned short)(__float_as_uint(q0) >> 16);
            xs[lds_h(p0 + 1, c)] = (unsigned short)(__float_as_uint(q1) >> 16);
            xs[lds_h(p0 + 2, c)] = (unsigned short)(__float_as_uint(q2) >> 16);
            xs[lds_h(p0 + 3, c)] = (unsigned short)(__float_as_uint(q3) >> 16);
        }
    }
    // ---- stage halo columns wp=0 (gw=w0-1), wp=33 (gw=w0+32): 640 elements
    #pragma unroll
    for (int it = 0; it < 3; ++it) {
        int e = tid + it * 256;
        if (e < 640) {
            int side = e & 1;
            int cc = (e >> 1) & 31;
            int hp = e >> 6;
            int gh = h0 - 1 + hp;
            int gw = side ? (w0 + 32) : (w0 - 1);
            float v = 0.f;
            if ((unsigned)gh < (unsigned)HW && (unsigned)gw < (unsigned)HW)
                v = xn[cc * PLANE + gh * HW + gw];
            float q = rintf(fminf(127.f, fmaxf(-128.f, v * inv)));
            xs[lds_h(hp * 34 + (side ? 33 : 0), cc)] =
                (unsigned short)(__float_as_uint(q) >> 16);
        }
    }
    __syncthreads();

    int ln = lane & 15, cb = lane >> 4;
    f32x4 acc[2][2][2] = {};  // [ri][pb][kb]

    // weights: 2 fragments per tap from global (18 KB, L1-resident), one-ahead prefetch
    const short8* wfp = (const short8*)wbuf;
    short8 wa = wfp[lane];
    short8 wb = wfp[64 + lane];
    for (int tap = 0; tap < 9; ++tap) {
        short8 na, nb;
        if (tap < 8) {
            na = wfp[(2 * tap + 2) * 64 + lane];
            nb = wfp[(2 * tap + 3) * 64 + lane];
        }
        int r = tap / 3;
        int s2 = tap - r * 3;
        #pragma unroll
        for (int ri = 0; ri < 2; ++ri) {
            #pragma unroll
            for (int pb = 0; pb < 2; ++pb) {
                int pix = (wv * 2 + ri + r) * 34 + pb * 16 + ln + s2;
                int sw = (pix & 3) ^ ((pix >> 2) & 3);
                const short8 a = *(const short8*)&xs[pix * 32 + (((cb ^ sw) & 3) << 3)];
                acc[ri][pb][0] = __builtin_amdgcn_mfma_f32_16x16x32_bf16(
                    a, wa, acc[ri][pb][0], 0, 0, 0);
                acc[ri][pb][1] = __builtin_amdgcn_mfma_f32_16x16x32_bf16(
                    a, wb, acc[ri][pb][1], 0, 0, 0);
            }
        }
        wa = na;
        wb = nb;
    }

    // epilogue: A=x so D row = pixel -> lane holds 4 consecutive pixels: float4 stores.
    // D: col = lane&15 = kout (within kb), row = (lane>>4)*4 + reg = pixel (within 16)
    float osc = scal[0];
    float* on = out + n * (NCH * PLANE);
    #pragma unroll
    for (int ri = 0; ri < 2; ++ri) {
        int h = h0 + wv * 2 + ri;
        #pragma unroll
        for (int pb = 0; pb < 2; ++pb) {
            int wcol = w0 + pb * 16 + cb * 4;
            #pragma unroll
            for (int kb = 0; kb < 2; ++kb) {
                int k = kb * 16 + ln;
                float4 o;
                o.x = acc[ri][pb][kb][0] * osc;
                o.y = acc[ri][pb][kb][1] * osc;
                o.z = acc[ri][pb][kb][2] * osc;
                o.w = acc[ri][pb][kb][3] * osc;
                *(float4*)&on[(k * HW + h) * HW + wcol] = o;
            }
        }
    }
}

extern "C" void kernel_launch(void* const* d_in, const int* in_sizes, int n_in,
                              void* d_out, int out_size, void* d_ws, size_t ws_size,
                              hipStream_t stream)
{
    const float* x = (const float*)d_in[0];
    const float* w = (const float*)d_in[1];
    float* outp = (float*)d_out;
    unsigned* slots = (unsigned*)d_ws;
    float* scal = (float*)((char*)d_ws + 4096);
    unsigned short* wbuf = (unsigned short*)((char*)d_ws + 4608);

    hipMemsetAsync(d_ws, 0, 4096, stream);

    int n4 = (16 * NCH * PLANE) / 4;
    absmax_kernel<<<2048, 256, 0, stream>>>(x, slots, n4);
    prep_kernel<<<1, 256, 0, stream>>>(w, slots, scal, wbuf);
    conv_kernel<<<16 * 28 * 7, 256, 0, stream>>>(x, wbuf, scal, outp);
}

// Round 4
// 92.880 us; speedup vs baseline: 1.7128x; 1.0274x over previous
//
#include <hip/hip_runtime.h>

// BitConv2d: x (16,32,224,224) f32, w (32,32,3,3) f32, out (16,32,224,224) f32.
// out = conv(x_q, w_q) * (x_scale/127 * w_scale); x_q in [-128,127], w_q in {-1,0,1}.
// Both exact in bf16 -> bf16 MFMA computes the integer conv exactly (|sum| < 2^24).

typedef __attribute__((ext_vector_type(8))) short short8;
typedef __attribute__((ext_vector_type(4))) float f32x4;

#define HW    224
#define NCH   32
#define PLANE (HW * HW)   // 50176
#define TH 16
#define TW 32
// LDS tile: 612 pixels (18 rows x 34 cols) x 32 ch bf16 = 39168 B, granule-XOR swizzled.

// halfword index: pixel-major, channel-last, 16B granule (8ch) XOR-swizzled so
// frag reads (pix stride 1 across lanes) and staging writes (pix stride 4) both
// spread across bank quads.
__device__ __forceinline__ int lds_h(int pix, int c) {
    int sw = (pix & 3) ^ ((pix >> 2) & 3);
    return pix * 32 + (c & 7) + ((((c >> 3) ^ sw) & 3) << 3);
}

// ws layout: [0, 8192) = u32 slots[2048] (per-block maxima, fully rewritten each call);
// 8192: scal[0]=out_scale, scal[1]=127/xscale; 8448: wbuf 18 frags x 512 bf16.

__global__ __launch_bounds__(256) void absmax_kernel(const float* __restrict__ x,
                                                     unsigned* __restrict__ slots, int n4)
{
    const float4* x4 = (const float4*)x;
    float m = 0.f;
    int stride = gridDim.x * blockDim.x;
    for (int i = blockIdx.x * blockDim.x + threadIdx.x; i < n4; i += stride) {
        float4 v = x4[i];
        m = fmaxf(m, fmaxf(fmaxf(fabsf(v.x), fabsf(v.y)),
                           fmaxf(fabsf(v.z), fabsf(v.w))));
    }
    #pragma unroll
    for (int off = 32; off > 0; off >>= 1)
        m = fmaxf(m, __shfl_xor(m, off));
    __shared__ float wm[4];
    int lane = threadIdx.x & 63, wv = threadIdx.x >> 6;
    if (lane == 0) wm[wv] = m;
    __syncthreads();
    if (threadIdx.x == 0) {
        m = fmaxf(fmaxf(wm[0], wm[1]), fmaxf(wm[2], wm[3]));
        slots[blockIdx.x] = __float_as_uint(m);  // plain store, no atomics
    }
}

// frag (tap*2+kb): lane l elem j = w_q[kout = kb*16+(l&15)][c = (l>>4)*8+j][tap/3][tap%3]
__global__ __launch_bounds__(256) void prep_kernel(const float* __restrict__ w,
                                                   const unsigned* __restrict__ slots,
                                                   float* __restrict__ scal,
                                                   unsigned short* __restrict__ wbuf)
{
    float s = 0.f;
    for (int i = threadIdx.x; i < 9216; i += 256) s += fabsf(w[i]);
    float m = 0.f;
    for (int i = threadIdx.x; i < 2048; i += 256)
        m = fmaxf(m, __uint_as_float(slots[i]));
    #pragma unroll
    for (int off = 32; off > 0; off >>= 1) {
        s += __shfl_xor(s, off);
        m = fmaxf(m, __shfl_xor(m, off));
    }
    __shared__ float sm[4], mm[4];
    __shared__ float s_ws;
    int lane = threadIdx.x & 63, wv = threadIdx.x >> 6;
    if (lane == 0) { sm[wv] = s; mm[wv] = m; }
    __syncthreads();
    if (threadIdx.x == 0) {
        float wscale = (sm[0] + sm[1] + sm[2] + sm[3]) / 9216.f + 1e-5f;
        float xscale = fmaxf(fmaxf(mm[0], mm[1]), fmaxf(mm[2], mm[3])) + 1e-5f;
        scal[0] = (xscale / 127.f) * wscale;  // epilogue scale
        scal[1] = 127.f / xscale;             // x quant scale
        s_ws = wscale;
    }
    __syncthreads();
    float wscale = s_ws;
    for (int o = threadIdx.x; o < 9216; o += 256) {
        int frag = o >> 9, rem = o & 511;
        int l = rem >> 3, j = rem & 7;
        int tap = frag >> 1, kb = frag & 1;
        int kout = kb * 16 + (l & 15);
        int c = ((l >> 4) << 3) + j;
        int r = tap / 3, ss = tap % 3;
        float wv2 = w[((kout * 32 + c) * 3 + r) * 3 + ss];
        float q = fminf(1.f, fmaxf(-1.f, rintf(wv2 / wscale)));
        wbuf[o] = (unsigned short)(__float_as_uint(q) >> 16);  // exact bf16 of {-1,0,1}
    }
}

__global__ __launch_bounds__(512, 4) void conv_kernel(const float* __restrict__ x,
                                                      const unsigned short* __restrict__ wbuf,
                                                      const float* __restrict__ scal,
                                                      float* __restrict__ out)
{
    __shared__ __align__(16) unsigned short xs[612 * 32];

    // bijective XCD swizzle: 1568 blocks = 8 XCDs x 196 contiguous
    int bid = (blockIdx.x & 7) * 196 + (blockIdx.x >> 3);
    int tw = bid % 7;
    int rest = bid / 7;
    int th = rest % 14;
    int n  = rest / 14;
    int h0 = th * TH, w0 = tw * TW;

    int tid = threadIdx.x;
    int lane = tid & 63, wv = tid >> 6;

    float inv = scal[1];
    const float* xn = x + n * (NCH * PLANE);

    // ---- stage interior cols [w0, w0+32): thread = (half = tid>>8, c = (tid>>3)&31,
    // slot = tid&7); each thread covers 9 of the 18 halo rows.
    {
        int slot = tid & 7;
        int c = (tid >> 3) & 31;
        int half = tid >> 8;
        const float* tb = xn + c * PLANE + w0 + slot * 4;
        int pixb = 1 + slot * 4;
        int hbase = half * 9;
        #pragma unroll 3
        for (int i = 0; i < 9; ++i) {
            int hp = hbase + i;
            int gh = h0 - 1 + hp;
            float4 v = {0.f, 0.f, 0.f, 0.f};
            if ((unsigned)gh < (unsigned)HW) v = *(const float4*)(tb + gh * HW);
            int p0 = hp * 34 + pixb;
            float q0 = rintf(fminf(127.f, fmaxf(-128.f, v.x * inv)));
            float q1 = rintf(fminf(127.f, fmaxf(-128.f, v.y * inv)));
            float q2 = rintf(fminf(127.f, fmaxf(-128.f, v.z * inv)));
            float q3 = rintf(fminf(127.f, fmaxf(-128.f, v.w * inv)));
            xs[lds_h(p0 + 0, c)] = (unsigned short)(__float_as_uint(q0) >> 16);
            xs[lds_h(p0 + 1, c)] = (unsigned short)(__float_as_uint(q1) >> 16);
            xs[lds_h(p0 + 2, c)] = (unsigned short)(__float_as_uint(q2) >> 16);
            xs[lds_h(p0 + 3, c)] = (unsigned short)(__float_as_uint(q3) >> 16);
        }
    }
    // ---- stage halo columns wp=0 (gw=w0-1), wp=33 (gw=w0+32): 18*32*2 = 1152 elems
    #pragma unroll
    for (int it = 0; it < 3; ++it) {
        int e = tid + it * 512;
        if (e < 1152) {
            int side = e & 1;
            int cc = (e >> 1) & 31;
            int hp = e >> 6;
            int gh = h0 - 1 + hp;
            int gw = side ? (w0 + 32) : (w0 - 1);
            float v = 0.f;
            if ((unsigned)gh < (unsigned)HW && (unsigned)gw < (unsigned)HW)
                v = xn[cc * PLANE + gh * HW + gw];
            float q = rintf(fminf(127.f, fmaxf(-128.f, v * inv)));
            xs[lds_h(hp * 34 + (side ? 33 : 0), cc)] =
                (unsigned short)(__float_as_uint(q) >> 16);
        }
    }
    __syncthreads();

    int ln = lane & 15, cb = lane >> 4;
    f32x4 acc[2][2][2] = {};  // [ri][pb][kb]

    // weights: 2 fragments per tap from global (18 KB, L1/L2-resident), one-ahead prefetch
    const short8* wfp = (const short8*)wbuf;
    short8 wa = wfp[lane];
    short8 wb = wfp[64 + lane];
    for (int tap = 0; tap < 9; ++tap) {
        short8 na, nb;
        if (tap < 8) {
            na = wfp[(2 * tap + 2) * 64 + lane];
            nb = wfp[(2 * tap + 3) * 64 + lane];
        }
        int r = tap / 3;
        int s2 = tap - r * 3;
        #pragma unroll
        for (int ri = 0; ri < 2; ++ri) {
            #pragma unroll
            for (int pb = 0; pb < 2; ++pb) {
                int pix = (wv * 2 + ri + r) * 34 + pb * 16 + ln + s2;
                int sw = (pix & 3) ^ ((pix >> 2) & 3);
                const short8 a = *(const short8*)&xs[pix * 32 + (((cb ^ sw) & 3) << 3)];
                acc[ri][pb][0] = __builtin_amdgcn_mfma_f32_16x16x32_bf16(
                    a, wa, acc[ri][pb][0], 0, 0, 0);
                acc[ri][pb][1] = __builtin_amdgcn_mfma_f32_16x16x32_bf16(
                    a, wb, acc[ri][pb][1], 0, 0, 0);
            }
        }
        wa = na;
        wb = nb;
    }

    // epilogue: A=x so D row = pixel -> lane holds 4 consecutive pixels: float4 stores.
    // D: col = lane&15 = kout (within kb), row = (lane>>4)*4 + reg = pixel (within 16)
    float osc = scal[0];
    float* on = out + n * (NCH * PLANE);
    #pragma unroll
    for (int ri = 0; ri < 2; ++ri) {
        int h = h0 + wv * 2 + ri;
        #pragma unroll
        for (int pb = 0; pb < 2; ++pb) {
            int wcol = w0 + pb * 16 + cb * 4;
            #pragma unroll
            for (int kb = 0; kb < 2; ++kb) {
                int k = kb * 16 + ln;
                f32x4 o;
                o[0] = acc[ri][pb][kb][0] * osc;
                o[1] = acc[ri][pb][kb][1] * osc;
                o[2] = acc[ri][pb][kb][2] * osc;
                o[3] = acc[ri][pb][kb][3] * osc;
                __builtin_nontemporal_store(o, (f32x4*)&on[(k * HW + h) * HW + wcol]);
            }
        }
    }
}

extern "C" void kernel_launch(void* const* d_in, const int* in_sizes, int n_in,
                              void* d_out, int out_size, void* d_ws, size_t ws_size,
                              hipStream_t stream)
{
    const float* x = (const float*)d_in[0];
    const float* w = (const float*)d_in[1];
    float* outp = (float*)d_out;
    unsigned* slots = (unsigned*)d_ws;
    float* scal = (float*)((char*)d_ws + 8192);
    unsigned short* wbuf = (unsigned short*)((char*)d_ws + 8448);

    int n4 = (16 * NCH * PLANE) / 4;
    absmax_kernel<<<2048, 256, 0, stream>>>(x, slots, n4);
    prep_kernel<<<1, 256, 0, stream>>>(w, slots, scal, wbuf);
    conv_kernel<<<16 * 14 * 7, 512, 0, stream>>>(x, wbuf, scal, outp);
}

// Round 6
// 87.872 us; speedup vs baseline: 1.8104x; 1.0570x over previous
//
#include <hip/hip_runtime.h>

// BitConv2d: x (16,32,224,224) f32, w (32,32,3,3) f32, out (16,32,224,224) f32.
// out = conv(x_q, w_q) * (x_scale/127 * w_scale); x_q in [-128,127], w_q in {-1,0,1}.
// Both exact in bf16 -> bf16 MFMA computes the integer conv exactly (|sum| < 2^24).

typedef __attribute__((ext_vector_type(8))) short short8;
typedef __attribute__((ext_vector_type(4))) float f32x4;

#define HW    224
#define NCH   32
#define PLANE (HW * HW)   // 50176
#define TH 16
#define TW 32
// LDS tile: 612 pixels (18 rows x 34 cols) x 32 ch bf16 = 39168 B, granule-XOR swizzled.

__device__ __forceinline__ int lds_h(int pix, int c) {
    int sw = (pix & 3) ^ ((pix >> 2) & 3);
    return pix * 32 + (c & 7) + ((((c >> 3) ^ sw) & 3) << 3);
}

// ws layout: [0, 8192) = u32 slots[2048] (per-block maxima, fully rewritten each call);
// 8192: scal[0]=out_scale, scal[1]=127/xscale; 8448: wbuf 18 frags x 512 bf16.

__global__ __launch_bounds__(256) void absmax_kernel(const float* __restrict__ x,
                                                     unsigned* __restrict__ slots, int n4)
{
    const float4* x4 = (const float4*)x;
    float m = 0.f;
    int stride = gridDim.x * blockDim.x;
    for (int i = blockIdx.x * blockDim.x + threadIdx.x; i < n4; i += stride) {
        float4 v = x4[i];
        m = fmaxf(m, fmaxf(fmaxf(fabsf(v.x), fabsf(v.y)),
                           fmaxf(fabsf(v.z), fabsf(v.w))));
    }
    #pragma unroll
    for (int off = 32; off > 0; off >>= 1)
        m = fmaxf(m, __shfl_xor(m, off));
    __shared__ float wm[4];
    int lane = threadIdx.x & 63, wv = threadIdx.x >> 6;
    if (lane == 0) wm[wv] = m;
    __syncthreads();
    if (threadIdx.x == 0) {
        m = fmaxf(fmaxf(wm[0], wm[1]), fmaxf(wm[2], wm[3]));
        slots[blockIdx.x] = __float_as_uint(m);  // plain store, no atomics
    }
}

// frag (tap*2+kb): lane l elem j = w_q[kout = kb*16+(l&15)][c = (l>>4)*8+j][tap/3][tap%3]
__global__ __launch_bounds__(256) void prep_kernel(const float* __restrict__ w,
                                                   const unsigned* __restrict__ slots,
                                                   float* __restrict__ scal,
                                                   unsigned short* __restrict__ wbuf)
{
    float s = 0.f;
    for (int i = threadIdx.x; i < 9216; i += 256) s += fabsf(w[i]);
    float m = 0.f;
    for (int i = threadIdx.x; i < 2048; i += 256)
        m = fmaxf(m, __uint_as_float(slots[i]));
    #pragma unroll
    for (int off = 32; off > 0; off >>= 1) {
        s += __shfl_xor(s, off);
        m = fmaxf(m, __shfl_xor(m, off));
    }
    __shared__ float sm[4], mm[4];
    __shared__ float s_ws;
    int lane = threadIdx.x & 63, wv = threadIdx.x >> 6;
    if (lane == 0) { sm[wv] = s; mm[wv] = m; }
    __syncthreads();
    if (threadIdx.x == 0) {
        float wscale = (sm[0] + sm[1] + sm[2] + sm[3]) / 9216.f + 1e-5f;
        float xscale = fmaxf(fmaxf(mm[0], mm[1]), fmaxf(mm[2], mm[3])) + 1e-5f;
        scal[0] = (xscale / 127.f) * wscale;  // epilogue scale
        scal[1] = 127.f / xscale;             // x quant scale
        s_ws = wscale;
    }
    __syncthreads();
    float wscale = s_ws;
    for (int o = threadIdx.x; o < 9216; o += 256) {
        int frag = o >> 9, rem = o & 511;
        int l = rem >> 3, j = rem & 7;
        int tap = frag >> 1, kb = frag & 1;
        int kout = kb * 16 + (l & 15);
        int c = ((l >> 4) << 3) + j;
        int r = tap / 3, ss = tap % 3;
        float wv2 = w[((kout * 32 + c) * 3 + r) * 3 + ss];
        float q = fminf(1.f, fmaxf(-1.f, rintf(wv2 / wscale)));
        wbuf[o] = (unsigned short)(__float_as_uint(q) >> 16);  // exact bf16 of {-1,0,1}
    }
}

__global__ __launch_bounds__(512, 4) void conv_kernel(const float* __restrict__ x,
                                                      const unsigned short* __restrict__ wbuf,
                                                      const float* __restrict__ scal,
                                                      float* __restrict__ out)
{
    __shared__ __align__(16) unsigned short xs[612 * 32];

    // bijective XCD swizzle: 1568 blocks = 8 XCDs x 196 contiguous
    int bid = (blockIdx.x & 7) * 196 + (blockIdx.x >> 3);
    int tw = bid % 7;
    int rest = bid / 7;
    int th = rest % 14;
    int n  = rest / 14;
    int h0 = th * TH, w0 = tw * TW;

    int tid = threadIdx.x;
    int lane = tid & 63, wv = tid >> 6;

    float inv = scal[1];
    const float* xn = x + n * (NCH * PLANE);

    // hoist first weight fragments: in flight during staging (L2-resident, 1 KB each)
    const short8* wfp = (const short8*)wbuf;
    short8 wa = wfp[lane];
    short8 wb = wfp[64 + lane];

    // ---- issue-early staging: all loads in flight before any quant/LDS write ----
    // interior cols [w0, w0+32): thread = (half = tid>>8, c = (tid>>3)&31, slot = tid&7)
    int slot = tid & 7;
    int c = (tid >> 3) & 31;
    int half = tid >> 8;
    const float* tb = xn + c * PLANE + w0 + slot * 4;
    int pixb = 1 + slot * 4;
    int hbase = half * 9;

    float4 v[9];
    float invr[9];
    #pragma unroll
    for (int i = 0; i < 9; ++i) {
        int gh = h0 - 1 + hbase + i;
        int ghc = gh < 0 ? 0 : (gh > HW - 1 ? HW - 1 : gh);
        invr[i] = (gh == ghc) ? inv : 0.f;   // OOB rows quantize to 0
        v[i] = *(const float4*)(tb + ghc * HW);   // always-safe clamped load
    }
    // halo columns wp=0 (gw=w0-1), wp=33 (gw=w0+32): 18*32*2 = 1152 elems
    float hv[3];
    #pragma unroll
    for (int it = 0; it < 3; ++it) {
        int e = tid + it * 512;
        hv[it] = 0.f;
        if (e < 1152) {
            int side = e & 1;
            int cc = (e >> 1) & 31;
            int hp = e >> 6;
            int gh = h0 - 1 + hp;
            int gw = side ? (w0 + TW) : (w0 - 1);
            int ghc = gh < 0 ? 0 : (gh > HW - 1 ? HW - 1 : gh);
            int gwc = gw < 0 ? 0 : (gw > HW - 1 ? HW - 1 : gw);
            float vv = xn[cc * PLANE + ghc * HW + gwc];
            hv[it] = (gh == ghc && gw == gwc) ? vv * inv : 0.f;
        }
    }
    // ---- quantize + LDS writes ----
    #pragma unroll
    for (int i = 0; i < 9; ++i) {
        int p0 = (hbase + i) * 34 + pixb;
        float q0 = rintf(fminf(127.f, fmaxf(-128.f, v[i].x * invr[i])));
        float q1 = rintf(fminf(127.f, fmaxf(-128.f, v[i].y * invr[i])));
        float q2 = rintf(fminf(127.f, fmaxf(-128.f, v[i].z * invr[i])));
        float q3 = rintf(fminf(127.f, fmaxf(-128.f, v[i].w * invr[i])));
        xs[lds_h(p0 + 0, c)] = (unsigned short)(__float_as_uint(q0) >> 16);
        xs[lds_h(p0 + 1, c)] = (unsigned short)(__float_as_uint(q1) >> 16);
        xs[lds_h(p0 + 2, c)] = (unsigned short)(__float_as_uint(q2) >> 16);
        xs[lds_h(p0 + 3, c)] = (unsigned short)(__float_as_uint(q3) >> 16);
    }
    #pragma unroll
    for (int it = 0; it < 3; ++it) {
        int e = tid + it * 512;
        if (e < 1152) {
            int side = e & 1;
            int cc = (e >> 1) & 31;
            int hp = e >> 6;
            float q = rintf(fminf(127.f, fmaxf(-128.f, hv[it])));
            xs[lds_h(hp * 34 + (side ? 33 : 0), cc)] =
                (unsigned short)(__float_as_uint(q) >> 16);
        }
    }
    __syncthreads();

    int ln = lane & 15, cb = lane >> 4;
    f32x4 acc[2][2][2] = {};  // [ri][pb][kb]

    for (int tap = 0; tap < 9; ++tap) {
        short8 na, nb;
        if (tap < 8) {
            na = wfp[(2 * tap + 2) * 64 + lane];
            nb = wfp[(2 * tap + 3) * 64 + lane];
        }
        int r = tap / 3;
        int s2 = tap - r * 3;
        #pragma unroll
        for (int ri = 0; ri < 2; ++ri) {
            #pragma unroll
            for (int pb = 0; pb < 2; ++pb) {
                int pix = (wv * 2 + ri + r) * 34 + pb * 16 + ln + s2;
                int sw = (pix & 3) ^ ((pix >> 2) & 3);
                const short8 a = *(const short8*)&xs[pix * 32 + (((cb ^ sw) & 3) << 3)];
                acc[ri][pb][0] = __builtin_amdgcn_mfma_f32_16x16x32_bf16(
                    a, wa, acc[ri][pb][0], 0, 0, 0);
                acc[ri][pb][1] = __builtin_amdgcn_mfma_f32_16x16x32_bf16(
                    a, wb, acc[ri][pb][1], 0, 0, 0);
            }
        }
        wa = na;
        wb = nb;
    }

    // epilogue: A=x so D row = pixel -> lane holds 4 consecutive pixels: float4 stores.
    // D: col = lane&15 = kout (within kb), row = (lane>>4)*4 + reg = pixel (within 16)
    float osc = scal[0];
    float* on = out + n * (NCH * PLANE);
    #pragma unroll
    for (int ri = 0; ri < 2; ++ri) {
        int h = h0 + wv * 2 + ri;
        #pragma unroll
        for (int pb = 0; pb < 2; ++pb) {
            int wcol = w0 + pb * 16 + cb * 4;
            #pragma unroll
            for (int kb = 0; kb < 2; ++kb) {
                int k = kb * 16 + ln;
                f32x4 o;
                o[0] = acc[ri][pb][kb][0] * osc;
                o[1] = acc[ri][pb][kb][1] * osc;
                o[2] = acc[ri][pb][kb][2] * osc;
                o[3] = acc[ri][pb][kb][3] * osc;
                *(f32x4*)&on[(k * HW + h) * HW + wcol] = o;   // plain store: L2 write-combine
            }
        }
    }
}

extern "C" void kernel_launch(void* const* d_in, const int* in_sizes, int n_in,
                              void* d_out, int out_size, void* d_ws, size_t ws_size,
                              hipStream_t stream)
{
    const float* x = (const float*)d_in[0];
    const float* w = (const float*)d_in[1];
    float* outp = (float*)d_out;
    unsigned* slots = (unsigned*)d_ws;
    float* scal = (float*)((char*)d_ws + 8192);
    unsigned short* wbuf = (unsigned short*)((char*)d_ws + 8448);

    int n4 = (16 * NCH * PLANE) / 4;
    absmax_kernel<<<2048, 256, 0, stream>>>(x, slots, n4);
    prep_kernel<<<1, 256, 0, stream>>>(w, slots, scal, wbuf);
    conv_kernel<<<16 * 14 * 7, 512, 0, stream>>>(x, wbuf, scal, outp);
}